// Round 18
// baseline (185.904 us; speedup 1.0000x reference)
//
#include <hip/hip_runtime.h>

typedef float f32x4 __attribute__((ext_vector_type(4)));
typedef unsigned long long ull;

#define OFF_PRED 26214400      // 32*128*128*50
#define OFF_XU   56934400      // OFF_PRED + 32*64*300*50
#define LROW 328               // LDS row stride bytes (fp8): 320 + 8 pad

// pack 4 floats into 4 fp8 e4m3 bytes (one u32)
__device__ inline unsigned pack4_fp8(float a, float b, float c, float d) {
    int r = __builtin_amdgcn_cvt_pk_fp8_f32(a, b, 0, false);   // bytes 0,1
    r = __builtin_amdgcn_cvt_pk_fp8_f32(c, d, r, true);        // bytes 2,3
    return (unsigned)r;
}

// ---- K0: build M in MFMA-fragment order, fp8.
// Logical M[640][320]: rows 0..255 = C, 256..555 = A, rest 0; cols k<300 real, else 0.
// frag elem byte = ((mt*10+ks)*64 + lane)*8 + e ; m = mt*16+(lane&15), k = ks*32+(lane>>4)*8+e.
__global__ void build_M(const float* __restrict__ A, const float* __restrict__ C,
                        unsigned* __restrict__ M) {
    int idx = blockIdx.x * 256 + threadIdx.x;      // u32 index (4 fp8 elems)
    if (idx >= 51200) return;                      // 640*320/4
    int d = idx * 4;
    int e0 = d & 7, lane = (d >> 3) & 63, fs = d >> 9;
    int mt = fs / 10, ks = fs % 10;
    int m = mt * 16 + (lane & 15);
    int k = ks * 32 + (lane >> 4) * 8 + e0;
    float f0 = 0.f, f1 = 0.f, f2 = 0.f, f3 = 0.f;
    const float* src = nullptr;
    if (m < 256) src = C + m * 300;
    else if (m < 556) src = A + (m - 256) * 300;
    if (src) {
        if (k + 0 < 300) f0 = src[k + 0];
        if (k + 1 < 300) f1 = src[k + 1];
        if (k + 2 < 300) f2 = src[k + 2];
        if (k + 3 < 300) f3 = src[k + 3];
    }
    M[idx] = pack4_fp8(f0, f1, f2, f3);
}

// ---- K1: one block per bp (2048 blocks, XCD-swizzled), 256 thr / 4 waves.
//      Stage [x0|X_bp] -> fp8 LDS ONCE, then TWO passes (mh = 0,1) each computing
//      m-rows [mh*320, mh*320+320): wave g owns 5 mt x 4 n-tiles, acc 5x4=80.
//      M streamed fp8 (frag-ordered, L2-resident). launch_bounds(256,3) -> 3 blocks/CU.
__global__ __launch_bounds__(256, 3) void gemm_main(
    const float* __restrict__ X, const float* __restrict__ x0,
    const char* __restrict__ M, float* __restrict__ out)
{
    __shared__ char ldsb[64 * LROW];               // 20992 B
    const int tid = threadIdx.x;
    const int bp = ((blockIdx.x & 7) << 8) + (blockIdx.x >> 3);   // 2048 = 8*256, bijective
    const int b = bp >> 6, p = bp & 63;
    const float* Xbp = X + bp * 15000;

    const int wave = tid >> 6, lane = tid & 63;
    const int lr = lane & 15, lg = lane >> 4;
    const int g = wave;

    // ---- zero only the pad bytes (disjoint from staged data -> one barrier) ----
    // (a) pad cols [300,328) of rows 0..50: 51*7 = 357 u32
    if (tid < 179) {
        int i = tid * 2;
        int row = i / 7, c = i % 7;
        *(unsigned*)(ldsb + row * LROW + 300 + c * 4) = 0u;
        if (i + 1 < 357) {
            int row2 = (i + 1) / 7, c2 = (i + 1) % 7;
            *(unsigned*)(ldsb + row2 * LROW + 300 + c2 * 4) = 0u;
        }
    }
    // (b) rows 51..63 fully zero: 13*328/8 = 533 ull (51*328 = 16728, 8-aligned)
    #pragma unroll
    for (int u = 0; u < 3; u++) {
        int i = tid + u * 256;
        if (i < 533) *(ull*)(ldsb + 16728 + i * 8) = 0ULL;
    }

    // ---- stage: x0 -> row 0; X -> rows 1..50 via aligned float2 t-pairs ----
    if (tid < 75) {
        f32x4 v = *(const f32x4*)(x0 + bp * 300 + tid * 4);
        *(unsigned*)(ldsb + tid * 4) = pack4_fp8(v.x, v.y, v.z, v.w);
    }
    #pragma unroll
    for (int u = 0; u < 8; u++) {
        int i = tid + u * 256;
        if (i < 1875) {
            int tp = i % 25, jq = i / 25;          // t = 2*tp, j = 4*jq
            const float* s = Xbp + jq * 200 + tp * 2;
            float2 v0 = *(const float2*)(s);
            float2 v1 = *(const float2*)(s + 50);
            float2 v2 = *(const float2*)(s + 100);
            float2 v3 = *(const float2*)(s + 150);
            *(unsigned*)(ldsb + (tp * 2 + 1) * LROW + jq * 4) =
                pack4_fp8(v0.x, v1.x, v2.x, v3.x);
            *(unsigned*)(ldsb + (tp * 2 + 2) * LROW + jq * 4) =
                pack4_fp8(v0.y, v1.y, v2.y, v3.y);
        }
    }
    __syncthreads();

    const int gr = p >> 3, gc = p & 7;

    // ---- two passes over the same LDS tile: mh = 0 (rows 0..319), 1 (320..639) ----
    #pragma unroll 1
    for (int mh = 0; mh < 2; mh++) {
        const char* Mw = M + (((mh * 20 + g * 5) * 10) * 64) * 8 + lane * 8;

        f32x4 acc[5][4];
        #pragma unroll
        for (int j = 0; j < 5; j++)
            #pragma unroll
            for (int nt = 0; nt < 4; nt++)
                acc[j][nt] = (f32x4){0.f, 0.f, 0.f, 0.f};

        #pragma unroll
        for (int ks = 0; ks < 10; ks++) {
            long long m0 = *(const long long*)(Mw + (0 * 10 + ks) * 512);
            long long m1 = *(const long long*)(Mw + (1 * 10 + ks) * 512);
            long long m2 = *(const long long*)(Mw + (2 * 10 + ks) * 512);
            long long m3 = *(const long long*)(Mw + (3 * 10 + ks) * 512);
            long long m4 = *(const long long*)(Mw + (4 * 10 + ks) * 512);
            long long a0 = *(const long long*)(ldsb + (0 * 16 + lr) * LROW + ks * 32 + lg * 8);
            long long a1 = *(const long long*)(ldsb + (1 * 16 + lr) * LROW + ks * 32 + lg * 8);
            long long a2 = *(const long long*)(ldsb + (2 * 16 + lr) * LROW + ks * 32 + lg * 8);
            long long a3 = *(const long long*)(ldsb + (3 * 16 + lr) * LROW + ks * 32 + lg * 8);
            #pragma unroll
            for (int j = 0; j < 5; j++) {
                long long mm = (j == 0) ? m0 : (j == 1) ? m1 : (j == 2) ? m2 : (j == 3) ? m3 : m4;
                acc[j][0] = __builtin_amdgcn_mfma_f32_16x16x32_fp8_fp8(a0, mm, acc[j][0], 0, 0, 0);
                acc[j][1] = __builtin_amdgcn_mfma_f32_16x16x32_fp8_fp8(a1, mm, acc[j][1], 0, 0, 0);
                acc[j][2] = __builtin_amdgcn_mfma_f32_16x16x32_fp8_fp8(a2, mm, acc[j][2], 0, 0, 0);
                acc[j][3] = __builtin_amdgcn_mfma_f32_16x16x32_fp8_fp8(a3, mm, acc[j][3], 0, 0, 0);
            }
        }

        // ---- epilogue: col m = mh*320 + g*80 + j*16 + lr, ext-col n = nt*16 + lg*4 + q ----
        #pragma unroll
        for (int j = 0; j < 5; j++) {
            int colm = mh * 320 + g * 80 + j * 16 + lr;
            if (colm < 256) {
                // recon row d -> vid[b][gr*16 + d/16][gc*16 + d%16][t], t = n-1
                int base = b * 819200 + ((gr * 16 + (colm >> 4)) * 128 + gc * 16 + (colm & 15)) * 50;
                #pragma unroll
                for (int nt = 0; nt < 4; nt++) {
                    int t0 = nt * 16 + lg * 4;
                    if (t0 == 0) {
                        out[base + 0] = acc[j][0][1];
                        out[base + 1] = acc[j][0][2];
                        out[base + 2] = acc[j][0][3];
                    } else if (t0 <= 46) {
                        f32x4 v = acc[j][nt];
                        __builtin_memcpy(&out[base + t0 - 1], &v, 16);
                    } else if (t0 == 48) {
                        out[base + 47] = acc[j][nt][0];
                        out[base + 48] = acc[j][nt][1];
                        out[base + 49] = acc[j][nt][2];
                    }
                }
            } else if (colm < 556) {
                // X_pred row i = colm-256, t = n
                int base = OFF_PRED + (bp * 300 + (colm - 256)) * 50;
                #pragma unroll
                for (int nt = 0; nt < 4; nt++) {
                    int t0 = nt * 16 + lg * 4;
                    if (t0 <= 46) {
                        f32x4 v = acc[j][nt];
                        __builtin_memcpy(&out[base + t0], &v, 16);
                    } else if (t0 == 48) {
                        out[base + 48] = acc[j][nt][0];
                        out[base + 49] = acc[j][nt][1];
                    }
                }
            }
        }
    }
}

// ---- K2: X_U[b,i,t] = 0.5*(1+exp(-(B·U)[b,i,t])) * sum_p |X[b,p,i,t]|
__global__ void xu_kernel(const float* __restrict__ X, const float* __restrict__ U,
                          const float* __restrict__ B, float* __restrict__ out) {
    int id = blockIdx.x * 256 + threadIdx.x;
    if (id >= 480000) return;
    int t = id % 50;
    int i = (id / 50) % 300;
    int b = id / 15000;
    const float* xp = X + b * 960000 + i * 50 + t;
    float s = 0.f;
    #pragma unroll 8
    for (int pp = 0; pp < 64; pp++) s += fabsf(xp[pp * 15000]);
    float bu = 0.f;
    const float* up = U + b * 2000 + t;
    const float* Bp = B + i * 40;
    #pragma unroll 8
    for (int q = 0; q < 40; q++) bu += Bp[q] * up[q * 50];
    out[OFF_XU + id] = 0.5f * (1.f + expf(-bu)) * s;
}

extern "C" void kernel_launch(void* const* d_in, const int* in_sizes, int n_in,
                              void* d_out, int out_size, void* d_ws, size_t ws_size,
                              hipStream_t stream) {
    const float* X  = (const float*)d_in[0];
    const float* U  = (const float*)d_in[1];
    const float* x0 = (const float*)d_in[2];
    const float* A  = (const float*)d_in[3];
    const float* B  = (const float*)d_in[4];
    const float* C  = (const float*)d_in[5];
    float* out = (float*)d_out;
    unsigned* M = (unsigned*)d_ws;      // 640*320 fp8 = 204,800 B (fragment-ordered)

    build_M<<<200, 256, 0, stream>>>(A, C, M);
    gemm_main<<<2048, 256, 0, stream>>>(X, x0, (const char*)M, out);
    xu_kernel<<<1875, 256, 0, stream>>>(X, U, B, out);
}

// Round 19
// 157.775 us; speedup vs baseline: 1.1783x; 1.1783x over previous
//
#include <hip/hip_runtime.h>

typedef _Float16 half8 __attribute__((ext_vector_type(8)));
typedef _Float16 half4v __attribute__((ext_vector_type(4)));
typedef float f32x4 __attribute__((ext_vector_type(4)));
typedef unsigned long long ull;

#define OFF_PRED 26214400      // 32*128*128*50
#define OFF_XU   56934400      // OFF_PRED + 32*64*300*50

// ---- K0: build M in MFMA-fragment order, fp16 (R13-identical).
// Logical M[640][320]: rows 0..255 = C, 256..555 = A, rest 0; cols k<300 real, else 0.
// dst elem = ((mt*10 + ks)*64 + lane)*8 + e, m = mt*16 + (lane&15), k = ks*32 + (lane>>4)*8 + e.
__global__ void build_M(const float* __restrict__ A, const float* __restrict__ C,
                        _Float16* __restrict__ M) {
    int idx = blockIdx.x * 256 + threadIdx.x;
    if (idx >= 640 * 320) return;
    int e    = idx & 7;
    int lane = (idx >> 3) & 63;
    int fs   = idx >> 9;                        // mt*10 + ks
    int mt = fs / 10, ks = fs % 10;
    int m = mt * 16 + (lane & 15);
    int k = ks * 32 + (lane >> 4) * 8 + e;
    float v = 0.f;
    if (k < 300) {
        if (m < 256) v = C[m * 300 + k];
        else if (m < 556) v = A[(m - 256) * 300 + k];
    }
    M[idx] = (_Float16)v;
}

// ---- K1: FUSED kernel. 6144 blocks, 256 thr.
//      XCD swizzle over 8x768 chunks, then role split inside each chunk:
//      r = sw%3 < 2 -> GEMM block (gidx = 2q+r in [0,4096), (bp,mhalf) as R13);
//      r == 2     -> XU block (xq = q in [0,1875)).
//      xu blocks interleave with gemm blocks per-XCD -> their HBM reads overlap
//      gemm's latency bubbles instead of running serially afterwards.
__global__ __launch_bounds__(256, 3) void fused_main(
    const float* __restrict__ X, const float* __restrict__ x0,
    const _Float16* __restrict__ M, const float* __restrict__ U,
    const float* __restrict__ Bm, float* __restrict__ out)
{
    __shared__ _Float16 lds[64 * 320];   // 40960 B (gemm role only)
    const int tid = threadIdx.x;
    const int sw = ((blockIdx.x & 7) * 768) + (blockIdx.x >> 3);   // 6144 = 8*768, bijective
    const int q = sw / 3, r = sw - q * 3;

    if (r == 2) {
        // ================= XU role: X_U[b,i,t] = 0.5*(1+exp(-(B·U))) * sum_p |X| ====
        if (q >= 1875) return;
        int id = q * 256 + tid;
        if (id >= 480000) return;
        int t = id % 50;
        int i = (id / 50) % 300;
        int b = id / 15000;
        const float* xp = X + b * 960000 + i * 50 + t;
        float s = 0.f;
        #pragma unroll 8
        for (int pp = 0; pp < 64; pp++) s += fabsf(xp[pp * 15000]);
        float bu = 0.f;
        const float* up = U + b * 2000 + t;
        const float* Bp = Bm + i * 40;
        #pragma unroll 8
        for (int qq = 0; qq < 40; qq++) bu += Bp[qq] * up[qq * 50];
        out[OFF_XU + id] = 0.5f * (1.f + expf(-bu)) * s;
        return;
    }

    // ================= GEMM role (R13-identical math) =================
    char* ldsb = (char*)lds;
    const int gidx = q * 2 + r;                  // [0,4096), contiguous per XCD chunk
    const int bp = gidx >> 1, mhalf = gidx & 1;
    const int b = bp >> 6, p = bp & 63;
    const float* Xbp = X + bp * 15000;

    const int wave = tid >> 6, lane = tid & 63;
    const int lr = lane & 15, lg = lane >> 4;
    const int g = wave;

    // ---- single staging phase: pad-zero + x0 + X, disjoint bytes, ONE barrier ----
    // (a) pad cols [600,640) of rows 0..50 (swizzled, 8B chunks)
    if (tid < 255) {
        int row = tid / 5, c = tid % 5;
        *(ull*)(ldsb + row * 640 + ((600 + c * 8) ^ ((row & 7) << 4))) = 0ULL;
    }
    // (b) rows 51..63 fully zero — XOR swizzle permutes within a row, linear ok
    #pragma unroll
    for (int u = 0; u < 5; u++) {
        int i = tid + u * 256;
        if (i < 1040) *(ull*)(ldsb + 51 * 640 + i * 8) = 0ULL;
    }
    // (c) x0 -> row 0 (row 0 swizzle = identity)
    if (tid < 75) {
        f32x4 v = *(const f32x4*)(x0 + bp * 300 + tid * 4);
        half4v h4 = { (_Float16)v.x, (_Float16)v.y, (_Float16)v.z, (_Float16)v.w };
        *(half4v*)(ldsb + tid * 8) = h4;
    }
    // (d) X (k-major [300][50]) -> rows n=t+1 (transposed), 8B swizzled writes
    for (int i = tid; i < 3750; i += 256) {
        int t = i % 50, jq = i / 50;
        const float* s = Xbp + (jq * 4) * 50 + t;
        half4v h4 = { (_Float16)s[0], (_Float16)s[50], (_Float16)s[100], (_Float16)s[150] };
        int row = t + 1;
        *(half4v*)(ldsb + row * 640 + ((jq * 8) ^ ((row & 7) << 4))) = h4;
    }
    __syncthreads();

    f32x4 acc[5][4];
    #pragma unroll
    for (int j = 0; j < 5; j++)
        #pragma unroll
        for (int nt = 0; nt < 4; nt++)
            acc[j][nt] = (f32x4){0.f, 0.f, 0.f, 0.f};

    // B-frag (fragment-ordered M): global m-group = mhalf*4 + g, frag (mt,ks) = 1KB burst
    const _Float16* Mw = M + (mhalf * 4 + g) * 50 * 512 + lane * 8;
    // A-frag: row = nt*16 + lr
    #define LDSA(nt, ks) (*(const half8*)(ldsb + ((nt) * 16 + lr) * 640 + \
                         (((ks) * 64 + lg * 16) ^ ((lr & 7) << 4))))

    #pragma unroll
    for (int ks = 0; ks < 10; ks++) {
        half8 bf0 = *(const half8*)(Mw + (0 * 10 + ks) * 512);
        half8 bf1 = *(const half8*)(Mw + (1 * 10 + ks) * 512);
        half8 bf2 = *(const half8*)(Mw + (2 * 10 + ks) * 512);
        half8 bf3 = *(const half8*)(Mw + (3 * 10 + ks) * 512);
        half8 bf4 = *(const half8*)(Mw + (4 * 10 + ks) * 512);
        #pragma unroll
        for (int nt = 0; nt < 4; nt++) {
            half8 a = LDSA(nt, ks);
            acc[0][nt] = __builtin_amdgcn_mfma_f32_16x16x32_f16(a, bf0, acc[0][nt], 0, 0, 0);
            acc[1][nt] = __builtin_amdgcn_mfma_f32_16x16x32_f16(a, bf1, acc[1][nt], 0, 0, 0);
            acc[2][nt] = __builtin_amdgcn_mfma_f32_16x16x32_f16(a, bf2, acc[2][nt], 0, 0, 0);
            acc[3][nt] = __builtin_amdgcn_mfma_f32_16x16x32_f16(a, bf3, acc[3][nt], 0, 0, 0);
            acc[4][nt] = __builtin_amdgcn_mfma_f32_16x16x32_f16(a, bf4, acc[4][nt], 0, 0, 0);
        }
    }

    // epilogue: col m = mhalf*320 + g*80 + j*16 + lr, ext-col n = nt*16 + lg*4 + q
    const int gr = p >> 3, gc = p & 7;
    #pragma unroll
    for (int j = 0; j < 5; j++) {
        int colm = mhalf * 320 + g * 80 + j * 16 + lr;
        if (colm < 256) {
            // recon row d = colm -> vid[b][gr*16 + d/16][gc*16 + d%16][t], t = n-1
            int base = b * 819200 + ((gr * 16 + (colm >> 4)) * 128 + gc * 16 + (colm & 15)) * 50;
            #pragma unroll
            for (int nt = 0; nt < 4; nt++) {
                int t0 = nt * 16 + lg * 4;
                if (t0 == 0) {
                    out[base + 0] = acc[j][0][1];
                    out[base + 1] = acc[j][0][2];
                    out[base + 2] = acc[j][0][3];
                } else if (t0 <= 46) {
                    f32x4 v = acc[j][nt];
                    __builtin_memcpy(&out[base + t0 - 1], &v, 16);
                } else if (t0 == 48) {
                    out[base + 47] = acc[j][nt][0];
                    out[base + 48] = acc[j][nt][1];
                    out[base + 49] = acc[j][nt][2];
                }
            }
        } else if (colm < 556) {
            // X_pred row i = colm-256, t = n
            int base = OFF_PRED + (bp * 300 + (colm - 256)) * 50;
            #pragma unroll
            for (int nt = 0; nt < 4; nt++) {
                int t0 = nt * 16 + lg * 4;
                if (t0 <= 46) {
                    f32x4 v = acc[j][nt];
                    __builtin_memcpy(&out[base + t0], &v, 16);
                } else if (t0 == 48) {
                    out[base + 48] = acc[j][nt][0];
                    out[base + 49] = acc[j][nt][1];
                }
            }
        }
    }
    #undef LDSA
}

extern "C" void kernel_launch(void* const* d_in, const int* in_sizes, int n_in,
                              void* d_out, int out_size, void* d_ws, size_t ws_size,
                              hipStream_t stream) {
    const float* X  = (const float*)d_in[0];
    const float* U  = (const float*)d_in[1];
    const float* x0 = (const float*)d_in[2];
    const float* A  = (const float*)d_in[3];
    const float* B  = (const float*)d_in[4];
    const float* C  = (const float*)d_in[5];
    float* out = (float*)d_out;
    _Float16* M = (_Float16*)d_ws;      // 640*320*2 = 409,600 B (fragment-ordered)

    build_M<<<800, 256, 0, stream>>>(A, C, M);
    fused_main<<<6144, 256, 0, stream>>>(X, x0, M, U, B, out);
}

// Round 20
// 134.121 us; speedup vs baseline: 1.3861x; 1.1764x over previous
//
#include <hip/hip_runtime.h>

typedef _Float16 half8 __attribute__((ext_vector_type(8)));
typedef _Float16 half4v __attribute__((ext_vector_type(4)));
typedef float f32x4 __attribute__((ext_vector_type(4)));
typedef unsigned long long ull;

#define OFF_PRED 26214400      // 32*128*128*50
#define OFF_XU   56934400      // OFF_PRED + 32*64*300*50

// ---- K0: build M in MFMA-fragment order, fp16.
// Logical M[640][320]: rows 0..255 = C, 256..555 = A, rest 0; cols k<300 real, else 0.
// dst elem = ((mt*10 + ks)*64 + lane)*8 + e, m = mt*16 + (lane&15), k = ks*32 + (lane>>4)*8 + e.
__global__ void build_M(const float* __restrict__ A, const float* __restrict__ C,
                        _Float16* __restrict__ M) {
    int idx = blockIdx.x * 256 + threadIdx.x;
    if (idx >= 640 * 320) return;
    int e    = idx & 7;
    int lane = (idx >> 3) & 63;
    int fs   = idx >> 9;                        // mt*10 + ks
    int mt = fs / 10, ks = fs % 10;
    int m = mt * 16 + (lane & 15);
    int k = ks * 32 + (lane >> 4) * 8 + e;
    float v = 0.f;
    if (k < 300) {
        if (m < 256) v = C[m * 300 + k];
        else if (m < 556) v = A[(m - 256) * 300 + k];
    }
    M[idx] = (_Float16)v;
}

// ---- K1: block (bp, mhalf) — R13 structure (best verified: 139.8 µs total) +
//      float2-pair staging + ks=0 M-prefetch. 256 thr / 4 waves; wave g owns
//      m-rows [mhalf*320+80g, +80) (5 mt) x 4 n-tiles; acc = 5x4 = 80.
//      launch_bounds(256,3) -> 3 blocks/CU co-resident (cross-block phase overlap).
//      LDS: 64 rows x 320 fp16, stride 640 B, swz: byte ^ ((row&7)<<4).
//      XCD swizzle: hw b -> orig = (b&7)*512 + (b>>3) (4096 = 8*512, bijective).
__global__ __launch_bounds__(256, 3) void gemm_main(
    const float* __restrict__ X, const float* __restrict__ x0,
    const _Float16* __restrict__ M, float* __restrict__ out)
{
    __shared__ _Float16 lds[64 * 320];   // 40960 B
    char* ldsb = (char*)lds;
    const int orig = ((blockIdx.x & 7) << 9) + (blockIdx.x >> 3);
    const int bp = orig >> 1, mhalf = orig & 1;
    const int b = bp >> 6, p = bp & 63;
    const int tid = threadIdx.x;
    const float* Xbp = X + bp * 15000;

    const int wave = tid >> 6, lane = tid & 63;
    const int lr = lane & 15, lg = lane >> 4;
    const int g = wave;

    // B-frag base (fragment-ordered M): global m-group = mhalf*4 + g
    const _Float16* Mw = M + (mhalf * 4 + g) * 50 * 512 + lane * 8;

    // ---- prefetch ks=0 B-frags: loads fly during staging, kill K-loop entry stall ----
    half8 pf[5];
    #pragma unroll
    for (int j = 0; j < 5; j++) pf[j] = *(const half8*)(Mw + (j * 10) * 512);

    // ---- single staging phase: pad-zero + x0 + X, disjoint bytes, ONE barrier ----
    // (a) pad cols [600,640) of rows 0..50 (swizzled, 8B chunks): 51*5 = 255 items
    if (tid < 255) {
        int row = tid / 5, c = tid % 5;
        *(ull*)(ldsb + row * 640 + ((600 + c * 8) ^ ((row & 7) << 4))) = 0ULL;
    }
    // (b) rows 51..63 fully zero — XOR swizzle permutes within a row, linear ok
    #pragma unroll
    for (int u = 0; u < 5; u++) {
        int i = tid + u * 256;
        if (i < 1040) *(ull*)(ldsb + 51 * 640 + i * 8) = 0ULL;
    }
    // (c) x0 -> row 0 (row 0 swizzle = identity)
    if (tid < 75) {
        f32x4 v = *(const f32x4*)(x0 + bp * 300 + tid * 4);
        half4v h4 = { (_Float16)v.x, (_Float16)v.y, (_Float16)v.z, (_Float16)v.w };
        *(half4v*)(ldsb + tid * 8) = h4;
    }
    // (d) X (k-major [300][50]) -> rows n=t+1 (transposed), aligned float2 t-pairs
    //     item i in [0,1875): tp = i%25 (t = 2*tp), jq = i/25 (j = 4*jq)
    #pragma unroll
    for (int u = 0; u < 8; u++) {
        int i = tid + u * 256;
        if (i < 1875) {
            int tp = i % 25, jq = i / 25;
            const float* s = Xbp + jq * 200 + tp * 2;
            float2 v0 = *(const float2*)(s);
            float2 v1 = *(const float2*)(s + 50);
            float2 v2 = *(const float2*)(s + 100);
            float2 v3 = *(const float2*)(s + 150);
            int r1 = tp * 2 + 1, r2 = tp * 2 + 2;
            half4v h1 = { (_Float16)v0.x, (_Float16)v1.x, (_Float16)v2.x, (_Float16)v3.x };
            half4v h2 = { (_Float16)v0.y, (_Float16)v1.y, (_Float16)v2.y, (_Float16)v3.y };
            *(half4v*)(ldsb + r1 * 640 + ((jq * 8) ^ ((r1 & 7) << 4))) = h1;
            *(half4v*)(ldsb + r2 * 640 + ((jq * 8) ^ ((r2 & 7) << 4))) = h2;
        }
    }
    __syncthreads();

    f32x4 acc[5][4];
    #pragma unroll
    for (int j = 0; j < 5; j++)
        #pragma unroll
        for (int nt = 0; nt < 4; nt++)
            acc[j][nt] = (f32x4){0.f, 0.f, 0.f, 0.f};

    // A-frag: row = nt*16 + lr
    #define LDSA(nt, ks) (*(const half8*)(ldsb + ((nt) * 16 + lr) * 640 + \
                         (((ks) * 64 + lg * 16) ^ ((lr & 7) << 4))))

    #pragma unroll
    for (int ks = 0; ks < 10; ks++) {
        half8 bf0, bf1, bf2, bf3, bf4;
        if (ks == 0) {
            bf0 = pf[0]; bf1 = pf[1]; bf2 = pf[2]; bf3 = pf[3]; bf4 = pf[4];
        } else {
            bf0 = *(const half8*)(Mw + (0 * 10 + ks) * 512);
            bf1 = *(const half8*)(Mw + (1 * 10 + ks) * 512);
            bf2 = *(const half8*)(Mw + (2 * 10 + ks) * 512);
            bf3 = *(const half8*)(Mw + (3 * 10 + ks) * 512);
            bf4 = *(const half8*)(Mw + (4 * 10 + ks) * 512);
        }
        #pragma unroll
        for (int nt = 0; nt < 4; nt++) {
            half8 a = LDSA(nt, ks);
            acc[0][nt] = __builtin_amdgcn_mfma_f32_16x16x32_f16(a, bf0, acc[0][nt], 0, 0, 0);
            acc[1][nt] = __builtin_amdgcn_mfma_f32_16x16x32_f16(a, bf1, acc[1][nt], 0, 0, 0);
            acc[2][nt] = __builtin_amdgcn_mfma_f32_16x16x32_f16(a, bf2, acc[2][nt], 0, 0, 0);
            acc[3][nt] = __builtin_amdgcn_mfma_f32_16x16x32_f16(a, bf3, acc[3][nt], 0, 0, 0);
            acc[4][nt] = __builtin_amdgcn_mfma_f32_16x16x32_f16(a, bf4, acc[4][nt], 0, 0, 0);
        }
    }

    // epilogue: col m = mhalf*320 + g*80 + j*16 + lr, ext-col n = nt*16 + lg*4 + q
    const int gr = p >> 3, gc = p & 7;
    #pragma unroll
    for (int j = 0; j < 5; j++) {
        int colm = mhalf * 320 + g * 80 + j * 16 + lr;
        if (colm < 256) {
            // recon row d = colm -> vid[b][gr*16 + d/16][gc*16 + d%16][t], t = n-1
            int base = b * 819200 + ((gr * 16 + (colm >> 4)) * 128 + gc * 16 + (colm & 15)) * 50;
            #pragma unroll
            for (int nt = 0; nt < 4; nt++) {
                int t0 = nt * 16 + lg * 4;
                if (t0 == 0) {
                    out[base + 0] = acc[j][0][1];
                    out[base + 1] = acc[j][0][2];
                    out[base + 2] = acc[j][0][3];
                } else if (t0 <= 46) {
                    f32x4 v = acc[j][nt];
                    __builtin_memcpy(&out[base + t0 - 1], &v, 16);
                } else if (t0 == 48) {
                    out[base + 47] = acc[j][nt][0];
                    out[base + 48] = acc[j][nt][1];
                    out[base + 49] = acc[j][nt][2];
                }
            }
        } else if (colm < 556) {
            // X_pred row i = colm-256, t = n
            int base = OFF_PRED + (bp * 300 + (colm - 256)) * 50;
            #pragma unroll
            for (int nt = 0; nt < 4; nt++) {
                int t0 = nt * 16 + lg * 4;
                if (t0 <= 46) {
                    f32x4 v = acc[j][nt];
                    __builtin_memcpy(&out[base + t0], &v, 16);
                } else if (t0 == 48) {
                    out[base + 48] = acc[j][nt][0];
                    out[base + 49] = acc[j][nt][1];
                }
            }
        }
    }
    #undef LDSA
}

// ---- K2: X_U[b,i,t] = 0.5*(1+exp(-(B·U)[b,i,t])) * sum_p |X[b,p,i,t]|
__global__ void xu_kernel(const float* __restrict__ X, const float* __restrict__ U,
                          const float* __restrict__ B, float* __restrict__ out) {
    int id = blockIdx.x * 256 + threadIdx.x;
    if (id >= 480000) return;
    int t = id % 50;
    int i = (id / 50) % 300;
    int b = id / 15000;
    const float* xp = X + b * 960000 + i * 50 + t;
    float s = 0.f;
    #pragma unroll 8
    for (int pp = 0; pp < 64; pp++) s += fabsf(xp[pp * 15000]);
    float bu = 0.f;
    const float* up = U + b * 2000 + t;
    const float* Bp = B + i * 40;
    #pragma unroll 8
    for (int q = 0; q < 40; q++) bu += Bp[q] * up[q * 50];
    out[OFF_XU + id] = 0.5f * (1.f + expf(-bu)) * s;
}

extern "C" void kernel_launch(void* const* d_in, const int* in_sizes, int n_in,
                              void* d_out, int out_size, void* d_ws, size_t ws_size,
                              hipStream_t stream) {
    const float* X  = (const float*)d_in[0];
    const float* U  = (const float*)d_in[1];
    const float* x0 = (const float*)d_in[2];
    const float* A  = (const float*)d_in[3];
    const float* B  = (const float*)d_in[4];
    const float* C  = (const float*)d_in[5];
    float* out = (float*)d_out;
    _Float16* M = (_Float16*)d_ws;      // 640*320*2 = 409,600 B (fragment-ordered)

    build_M<<<800, 256, 0, stream>>>(A, C, M);
    gemm_main<<<4096, 256, 0, stream>>>(X, x0, M, out);
    xu_kernel<<<1875, 256, 0, stream>>>(X, U, B, out);
}

// Round 21
// 125.117 us; speedup vs baseline: 1.4858x; 1.0720x over previous
//
#include <hip/hip_runtime.h>

typedef _Float16 half8 __attribute__((ext_vector_type(8)));
typedef _Float16 half4v __attribute__((ext_vector_type(4)));
typedef float f32x4 __attribute__((ext_vector_type(4)));
typedef unsigned long long ull;

#define OFF_PRED 26214400      // 32*128*128*50
#define OFF_XU   56934400      // OFF_PRED + 32*64*300*50

// ---- K0: build M in MFMA-fragment order, fp16.
// Logical M[640][320]: rows 0..255 = C, 256..555 = A, rest 0; cols k<300 real, else 0.
// dst elem = ((mt*10 + ks)*64 + lane)*8 + e, m = mt*16 + (lane&15), k = ks*32 + (lane>>4)*8 + e.
__global__ void build_M(const float* __restrict__ A, const float* __restrict__ C,
                        _Float16* __restrict__ M) {
    int idx = blockIdx.x * 256 + threadIdx.x;
    if (idx >= 640 * 320) return;
    int e    = idx & 7;
    int lane = (idx >> 3) & 63;
    int fs   = idx >> 9;                        // mt*10 + ks
    int mt = fs / 10, ks = fs % 10;
    int m = mt * 16 + (lane & 15);
    int k = ks * 32 + (lane >> 4) * 8 + e;
    float v = 0.f;
    if (k < 300) {
        if (m < 256) v = C[m * 300 + k];
        else if (m < 556) v = A[(m - 256) * 300 + k];
    }
    M[idx] = (_Float16)v;
}

// ---- K1: block (bpp, mhalf) serves TWO bp (bp0 = 2bpp, bp1 = 2bpp+1).
//      256 thr / 4 waves; wave g owns m-rows [mhalf*320+80g, +80) (5 mt) x 4 n-tiles
//      x 2 tiles -> each M-fragment feeds 40 MFMAs (M L2 traffic halved vs R20).
//      acc = 2x5x4 = 160; crossing state = acc only (proven-safe pattern).
//      launch_bounds(256,2) -> 256-reg cap; LDS 2x40960 = 80 KB -> 2 blocks/CU.
//      XCD swizzle: sw = (b&7)*256 + b>>3 (2048 = 8*256, bijective).
__global__ __launch_bounds__(256, 2) void gemm_main(
    const float* __restrict__ X, const float* __restrict__ x0,
    const _Float16* __restrict__ M, float* __restrict__ out)
{
    __shared__ _Float16 lds[2 * 64 * 320];   // 81920 B
    char* ldsb = (char*)lds;
    const int sw = ((blockIdx.x & 7) << 8) + (blockIdx.x >> 3);
    const int bpp = sw >> 1, mhalf = sw & 1;
    const int bp0 = bpp * 2;
    const int tid = threadIdx.x;

    const int wave = tid >> 6, lane = tid & 63;
    const int lr = lane & 15, lg = lane >> 4;
    const int g = wave;

    // B-frag base (fragment-ordered M): global m-group = mhalf*4 + g
    const _Float16* Mw = M + (mhalf * 4 + g) * 50 * 512 + lane * 8;

    // prefetch ks=0 B-frags (fly during staging)
    half8 pf[5];
    #pragma unroll
    for (int j = 0; j < 5; j++) pf[j] = *(const half8*)(Mw + (j * 10) * 512);

    // ---- staging: pad-zero + x0 + X for BOTH tiles, disjoint bytes, ONE barrier ----
    #pragma unroll
    for (int tau = 0; tau < 2; tau++) {
        char* lb = ldsb + tau * 40960;
        // (a) pad cols [600,640) of rows 0..50 (swizzled 8B chunks): 255 items
        if (tid < 255) {
            int row = tid / 5, c = tid % 5;
            *(ull*)(lb + row * 640 + ((600 + c * 8) ^ ((row & 7) << 4))) = 0ULL;
        }
        // (b) rows 51..63 fully zero (swizzle permutes within row; linear ok)
        #pragma unroll
        for (int u = 0; u < 5; u++) {
            int i = tid + u * 256;
            if (i < 1040) *(ull*)(lb + 51 * 640 + i * 8) = 0ULL;
        }
    }
    // (c) x0 -> row 0 of each tile (row 0 swizzle = identity)
    if (tid < 150) {
        int tau = tid / 75, c = tid - tau * 75;
        f32x4 v = *(const f32x4*)(x0 + (bp0 + tau) * 300 + c * 4);
        half4v h4 = { (_Float16)v.x, (_Float16)v.y, (_Float16)v.z, (_Float16)v.w };
        *(half4v*)(ldsb + tau * 40960 + c * 8) = h4;
    }
    // (d) X -> rows 1..50 (transposed), aligned float2 t-pairs; 2*1875 items
    #pragma unroll
    for (int u = 0; u < 15; u++) {
        int i = tid + u * 256;
        if (i < 3750) {
            int tau = i / 1875, rem = i - tau * 1875;
            int tp = rem % 25, jq = rem / 25;
            const float* s = X + (bp0 + tau) * 15000 + jq * 200 + tp * 2;
            float2 v0 = *(const float2*)(s);
            float2 v1 = *(const float2*)(s + 50);
            float2 v2 = *(const float2*)(s + 100);
            float2 v3 = *(const float2*)(s + 150);
            char* lb = ldsb + tau * 40960;
            int r1 = tp * 2 + 1, r2 = tp * 2 + 2;
            half4v h1 = { (_Float16)v0.x, (_Float16)v1.x, (_Float16)v2.x, (_Float16)v3.x };
            half4v h2 = { (_Float16)v0.y, (_Float16)v1.y, (_Float16)v2.y, (_Float16)v3.y };
            *(half4v*)(lb + r1 * 640 + ((jq * 8) ^ ((r1 & 7) << 4))) = h1;
            *(half4v*)(lb + r2 * 640 + ((jq * 8) ^ ((r2 & 7) << 4))) = h2;
        }
    }
    __syncthreads();

    f32x4 acc0[5][4], acc1[5][4];
    #pragma unroll
    for (int j = 0; j < 5; j++)
        #pragma unroll
        for (int nt = 0; nt < 4; nt++) {
            acc0[j][nt] = (f32x4){0.f, 0.f, 0.f, 0.f};
            acc1[j][nt] = (f32x4){0.f, 0.f, 0.f, 0.f};
        }

    // A-frag: tile base TB, row = nt*16 + lr
    #define LDSA(TB, nt, ks) (*(const half8*)(ldsb + (TB) + ((nt) * 16 + lr) * 640 + \
                             (((ks) * 64 + lg * 16) ^ ((lr & 7) << 4))))

    #pragma unroll
    for (int ks = 0; ks < 10; ks++) {
        half8 bf0, bf1, bf2, bf3, bf4;
        if (ks == 0) {
            bf0 = pf[0]; bf1 = pf[1]; bf2 = pf[2]; bf3 = pf[3]; bf4 = pf[4];
        } else {
            bf0 = *(const half8*)(Mw + (0 * 10 + ks) * 512);
            bf1 = *(const half8*)(Mw + (1 * 10 + ks) * 512);
            bf2 = *(const half8*)(Mw + (2 * 10 + ks) * 512);
            bf3 = *(const half8*)(Mw + (3 * 10 + ks) * 512);
            bf4 = *(const half8*)(Mw + (4 * 10 + ks) * 512);
        }
        #pragma unroll
        for (int nt = 0; nt < 4; nt++) {
            half8 a = LDSA(0, nt, ks);
            acc0[0][nt] = __builtin_amdgcn_mfma_f32_16x16x32_f16(a, bf0, acc0[0][nt], 0, 0, 0);
            acc0[1][nt] = __builtin_amdgcn_mfma_f32_16x16x32_f16(a, bf1, acc0[1][nt], 0, 0, 0);
            acc0[2][nt] = __builtin_amdgcn_mfma_f32_16x16x32_f16(a, bf2, acc0[2][nt], 0, 0, 0);
            acc0[3][nt] = __builtin_amdgcn_mfma_f32_16x16x32_f16(a, bf3, acc0[3][nt], 0, 0, 0);
            acc0[4][nt] = __builtin_amdgcn_mfma_f32_16x16x32_f16(a, bf4, acc0[4][nt], 0, 0, 0);
        }
        #pragma unroll
        for (int nt = 0; nt < 4; nt++) {
            half8 a = LDSA(40960, nt, ks);
            acc1[0][nt] = __builtin_amdgcn_mfma_f32_16x16x32_f16(a, bf0, acc1[0][nt], 0, 0, 0);
            acc1[1][nt] = __builtin_amdgcn_mfma_f32_16x16x32_f16(a, bf1, acc1[1][nt], 0, 0, 0);
            acc1[2][nt] = __builtin_amdgcn_mfma_f32_16x16x32_f16(a, bf2, acc1[2][nt], 0, 0, 0);
            acc1[3][nt] = __builtin_amdgcn_mfma_f32_16x16x32_f16(a, bf3, acc1[3][nt], 0, 0, 0);
            acc1[4][nt] = __builtin_amdgcn_mfma_f32_16x16x32_f16(a, bf4, acc1[4][nt], 0, 0, 0);
        }
    }
    #undef LDSA

    // ---- epilogue for each tile: col m = mhalf*320 + g*80 + j*16 + lr,
    //      ext-col n = nt*16 + lg*4 + q ----
#define EPILOGUE(ACC, BP) { \
    const int b_ = (BP) >> 6, p_ = (BP) & 63; \
    const int gr_ = p_ >> 3, gc_ = p_ & 7; \
    _Pragma("unroll") \
    for (int j = 0; j < 5; j++) { \
        int colm = mhalf * 320 + g * 80 + j * 16 + lr; \
        if (colm < 256) { \
            int base = b_ * 819200 + ((gr_ * 16 + (colm >> 4)) * 128 + gc_ * 16 + (colm & 15)) * 50; \
            _Pragma("unroll") \
            for (int nt = 0; nt < 4; nt++) { \
                int t0 = nt * 16 + lg * 4; \
                if (t0 == 0) { \
                    out[base + 0] = ACC[j][0][1]; \
                    out[base + 1] = ACC[j][0][2]; \
                    out[base + 2] = ACC[j][0][3]; \
                } else if (t0 <= 46) { \
                    f32x4 v = ACC[j][nt]; \
                    __builtin_memcpy(&out[base + t0 - 1], &v, 16); \
                } else if (t0 == 48) { \
                    out[base + 47] = ACC[j][nt][0]; \
                    out[base + 48] = ACC[j][nt][1]; \
                    out[base + 49] = ACC[j][nt][2]; \
                } \
            } \
        } else if (colm < 556) { \
            int base = OFF_PRED + ((BP) * 300 + (colm - 256)) * 50; \
            _Pragma("unroll") \
            for (int nt = 0; nt < 4; nt++) { \
                int t0 = nt * 16 + lg * 4; \
                if (t0 <= 46) { \
                    f32x4 v = ACC[j][nt]; \
                    __builtin_memcpy(&out[base + t0], &v, 16); \
                } else if (t0 == 48) { \
                    out[base + 48] = ACC[j][nt][0]; \
                    out[base + 49] = ACC[j][nt][1]; \
                } \
            } \
        } \
    } }

    EPILOGUE(acc0, bp0);
    EPILOGUE(acc1, bp0 + 1);
#undef EPILOGUE
}

// ---- K2: X_U[b,i,t] = 0.5*(1+exp(-(B·U)[b,i,t])) * sum_p |X[b,p,i,t]|
__global__ void xu_kernel(const float* __restrict__ X, const float* __restrict__ U,
                          const float* __restrict__ B, float* __restrict__ out) {
    int id = blockIdx.x * 256 + threadIdx.x;
    if (id >= 480000) return;
    int t = id % 50;
    int i = (id / 50) % 300;
    int b = id / 15000;
    const float* xp = X + b * 960000 + i * 50 + t;
    float s = 0.f;
    #pragma unroll 8
    for (int pp = 0; pp < 64; pp++) s += fabsf(xp[pp * 15000]);
    float bu = 0.f;
    const float* up = U + b * 2000 + t;
    const float* Bp = B + i * 40;
    #pragma unroll 8
    for (int q = 0; q < 40; q++) bu += Bp[q] * up[q * 50];
    out[OFF_XU + id] = 0.5f * (1.f + expf(-bu)) * s;
}

extern "C" void kernel_launch(void* const* d_in, const int* in_sizes, int n_in,
                              void* d_out, int out_size, void* d_ws, size_t ws_size,
                              hipStream_t stream) {
    const float* X  = (const float*)d_in[0];
    const float* U  = (const float*)d_in[1];
    const float* x0 = (const float*)d_in[2];
    const float* A  = (const float*)d_in[3];
    const float* B  = (const float*)d_in[4];
    const float* C  = (const float*)d_in[5];
    float* out = (float*)d_out;
    _Float16* M = (_Float16*)d_ws;      // 640*320*2 = 409,600 B (fragment-ordered)

    build_M<<<800, 256, 0, stream>>>(A, C, M);
    gemm_main<<<2048, 256, 0, stream>>>(X, x0, M, out);
    xu_kernel<<<1875, 256, 0, stream>>>(X, U, B, out);
}

// Round 22
// 120.298 us; speedup vs baseline: 1.5454x; 1.0401x over previous
//
#include <hip/hip_runtime.h>

typedef float f32x4 __attribute__((ext_vector_type(4)));
typedef unsigned long long ull;

#define OFF_PRED 26214400      // 32*128*128*50
#define OFF_XU   56934400      // OFF_PRED + 32*64*300*50
#define LROW 328               // fp8 LDS row stride bytes: 320 + 8 pad
#define BUFSZ (64 * LROW)      // 20992 B per X-tile

// pack 4 floats into 4 fp8 e4m3 bytes (one u32)
__device__ inline unsigned pack4_fp8(float a, float b, float c, float d) {
    int r = __builtin_amdgcn_cvt_pk_fp8_f32(a, b, 0, false);   // bytes 0,1
    r = __builtin_amdgcn_cvt_pk_fp8_f32(c, d, r, true);        // bytes 2,3
    return (unsigned)r;
}

// ---- K0: build M in MFMA-fragment order, fp8 (R17-proven).
// Logical M[640][320]: rows 0..255 = C, 256..555 = A, rest 0; cols k<300 real, else 0.
// frag elem byte = ((mt*10+ks)*64 + lane)*8 + e ; m = mt*16+(lane&15), k = ks*32+(lane>>4)*8+e.
__global__ void build_M(const float* __restrict__ A, const float* __restrict__ C,
                        unsigned* __restrict__ M) {
    int idx = blockIdx.x * 256 + threadIdx.x;      // u32 index (4 fp8 elems)
    if (idx >= 51200) return;                      // 640*320/4
    int d = idx * 4;
    int e0 = d & 7, lane = (d >> 3) & 63, fs = d >> 9;
    int mt = fs / 10, ks = fs % 10;
    int m = mt * 16 + (lane & 15);
    int k = ks * 32 + (lane >> 4) * 8 + e0;
    float f0 = 0.f, f1 = 0.f, f2 = 0.f, f3 = 0.f;
    const float* src = nullptr;
    if (m < 256) src = C + m * 300;
    else if (m < 556) src = A + (m - 256) * 300;
    if (src) {
        if (k + 0 < 300) f0 = src[k + 0];
        if (k + 1 < 300) f1 = src[k + 1];
        if (k + 2 < 300) f2 = src[k + 2];
        if (k + 3 < 300) f3 = src[k + 3];
    }
    M[idx] = pack4_fp8(f0, f1, f2, f3);
}

// ---- K1: R21 structure, fp8 streams. Block (bpp, mhalf) serves bp0 = 2bpp, bp1 = 2bpp+1.
//      256 thr / 4 waves; wave g owns m-rows [mhalf*320+80g, +80) (5 mt) x 4 n-tiles
//      x 2 tiles (acc = 160; crossing state = acc only). M streamed fp8 (8B frags,
//      L2 traffic halved vs R21). LDS: 2 x fp8 tile [64 rows x 328 B] = 41984 B.
//      launch_bounds(256,2) -> 256-reg cap, 2 blocks/CU.
//      XCD swizzle: sw = (b&7)*256 + b>>3 (2048 = 8*256, bijective).
__global__ __launch_bounds__(256, 2) void gemm_main(
    const float* __restrict__ X, const float* __restrict__ x0,
    const char* __restrict__ M, float* __restrict__ out)
{
    __shared__ char ldsb[2 * BUFSZ];               // 41984 B
    const int sw = ((blockIdx.x & 7) << 8) + (blockIdx.x >> 3);
    const int bpp = sw >> 1, mhalf = sw & 1;
    const int bp0 = bpp * 2;
    const int tid = threadIdx.x;

    const int wave = tid >> 6, lane = tid & 63;
    const int lr = lane & 15, lg = lane >> 4;
    const int g = wave;

    // B-frag base (fp8 frag-ordered M): mt = (mhalf*4+g)*5 + j, frag (mt,ks) = 512B burst
    const char* Mw = M + ((mhalf * 4 + g) * 5 * 10) * 512 + lane * 8;

    // prefetch ks=0 B-frags (fly during staging)
    long long pf[5];
    #pragma unroll
    for (int j = 0; j < 5; j++) pf[j] = *(const long long*)(Mw + (j * 10) * 512);

    // ---- staging: pad-zero + x0 + X for BOTH tiles, disjoint bytes, ONE barrier ----
    // (a) pad cols [300,328) of rows 0..50: 51*7 = 357 u32 per tile
    #pragma unroll
    for (int u = 0; u < 2; u++) {
        int i = tid + u * 256;
        if (i < 357) {
            int row = i / 7, c = i % 7;
            *(unsigned*)(ldsb + row * LROW + 300 + c * 4) = 0u;
            *(unsigned*)(ldsb + BUFSZ + row * LROW + 300 + c * 4) = 0u;
        }
    }
    // (b) rows 51..63 fully zero: 13*328/8 = 533 ull per tile (51*328 = 16728, 8-aligned)
    #pragma unroll
    for (int u = 0; u < 3; u++) {
        int i = tid + u * 256;
        if (i < 533) {
            *(ull*)(ldsb + 16728 + i * 8) = 0ULL;
            *(ull*)(ldsb + BUFSZ + 16728 + i * 8) = 0ULL;
        }
    }
    // (c) x0 -> row 0 of each tile
    if (tid < 150) {
        int tau = tid / 75, c = tid - tau * 75;
        f32x4 v = *(const f32x4*)(x0 + (bp0 + tau) * 300 + c * 4);
        *(unsigned*)(ldsb + tau * BUFSZ + c * 4) = pack4_fp8(v.x, v.y, v.z, v.w);
    }
    // (d) X -> rows 1..50 (transposed), aligned float2 t-pairs; 2*1875 items
    #pragma unroll
    for (int u = 0; u < 15; u++) {
        int i = tid + u * 256;
        if (i < 3750) {
            int tau = i / 1875, rem = i - tau * 1875;
            int tp = rem % 25, jq = rem / 25;
            const float* s = X + (bp0 + tau) * 15000 + jq * 200 + tp * 2;
            float2 v0 = *(const float2*)(s);
            float2 v1 = *(const float2*)(s + 50);
            float2 v2 = *(const float2*)(s + 100);
            float2 v3 = *(const float2*)(s + 150);
            char* lb = ldsb + tau * BUFSZ;
            *(unsigned*)(lb + (tp * 2 + 1) * LROW + jq * 4) = pack4_fp8(v0.x, v1.x, v2.x, v3.x);
            *(unsigned*)(lb + (tp * 2 + 2) * LROW + jq * 4) = pack4_fp8(v0.y, v1.y, v2.y, v3.y);
        }
    }
    __syncthreads();

    f32x4 acc0[5][4], acc1[5][4];
    #pragma unroll
    for (int j = 0; j < 5; j++)
        #pragma unroll
        for (int nt = 0; nt < 4; nt++) {
            acc0[j][nt] = (f32x4){0.f, 0.f, 0.f, 0.f};
            acc1[j][nt] = (f32x4){0.f, 0.f, 0.f, 0.f};
        }

    // A-frag: tile base TB, row = nt*16 + lr, 8B at k-bytes ks*32 + lg*8
    #define LDSA(TB, nt, ks) (*(const long long*)(ldsb + (TB) + ((nt) * 16 + lr) * LROW + \
                             (ks) * 32 + lg * 8))

    #pragma unroll
    for (int ks = 0; ks < 10; ks++) {
        long long bf0, bf1, bf2, bf3, bf4;
        if (ks == 0) {
            bf0 = pf[0]; bf1 = pf[1]; bf2 = pf[2]; bf3 = pf[3]; bf4 = pf[4];
        } else {
            bf0 = *(const long long*)(Mw + (0 * 10 + ks) * 512);
            bf1 = *(const long long*)(Mw + (1 * 10 + ks) * 512);
            bf2 = *(const long long*)(Mw + (2 * 10 + ks) * 512);
            bf3 = *(const long long*)(Mw + (3 * 10 + ks) * 512);
            bf4 = *(const long long*)(Mw + (4 * 10 + ks) * 512);
        }
        #pragma unroll
        for (int nt = 0; nt < 4; nt++) {
            long long a = LDSA(0, nt, ks);
            acc0[0][nt] = __builtin_amdgcn_mfma_f32_16x16x32_fp8_fp8(a, bf0, acc0[0][nt], 0, 0, 0);
            acc0[1][nt] = __builtin_amdgcn_mfma_f32_16x16x32_fp8_fp8(a, bf1, acc0[1][nt], 0, 0, 0);
            acc0[2][nt] = __builtin_amdgcn_mfma_f32_16x16x32_fp8_fp8(a, bf2, acc0[2][nt], 0, 0, 0);
            acc0[3][nt] = __builtin_amdgcn_mfma_f32_16x16x32_fp8_fp8(a, bf3, acc0[3][nt], 0, 0, 0);
            acc0[4][nt] = __builtin_amdgcn_mfma_f32_16x16x32_fp8_fp8(a, bf4, acc0[4][nt], 0, 0, 0);
        }
        #pragma unroll
        for (int nt = 0; nt < 4; nt++) {
            long long a = LDSA(BUFSZ, nt, ks);
            acc1[0][nt] = __builtin_amdgcn_mfma_f32_16x16x32_fp8_fp8(a, bf0, acc1[0][nt], 0, 0, 0);
            acc1[1][nt] = __builtin_amdgcn_mfma_f32_16x16x32_fp8_fp8(a, bf1, acc1[1][nt], 0, 0, 0);
            acc1[2][nt] = __builtin_amdgcn_mfma_f32_16x16x32_fp8_fp8(a, bf2, acc1[2][nt], 0, 0, 0);
            acc1[3][nt] = __builtin_amdgcn_mfma_f32_16x16x32_fp8_fp8(a, bf3, acc1[3][nt], 0, 0, 0);
            acc1[4][nt] = __builtin_amdgcn_mfma_f32_16x16x32_fp8_fp8(a, bf4, acc1[4][nt], 0, 0, 0);
        }
    }
    #undef LDSA

    // ---- epilogue: col m = mhalf*320 + g*80 + j*16 + lr, ext-col n = nt*16 + lg*4 + q ----
#define EPILOGUE(ACC, BP) { \
    const int b_ = (BP) >> 6, p_ = (BP) & 63; \
    const int gr_ = p_ >> 3, gc_ = p_ & 7; \
    _Pragma("unroll") \
    for (int j = 0; j < 5; j++) { \
        int colm = mhalf * 320 + g * 80 + j * 16 + lr; \
        if (colm < 256) { \
            int base = b_ * 819200 + ((gr_ * 16 + (colm >> 4)) * 128 + gc_ * 16 + (colm & 15)) * 50; \
            _Pragma("unroll") \
            for (int nt = 0; nt < 4; nt++) { \
                int t0 = nt * 16 + lg * 4; \
                if (t0 == 0) { \
                    out[base + 0] = ACC[j][0][1]; \
                    out[base + 1] = ACC[j][0][2]; \
                    out[base + 2] = ACC[j][0][3]; \
                } else if (t0 <= 46) { \
                    f32x4 v = ACC[j][nt]; \
                    __builtin_memcpy(&out[base + t0 - 1], &v, 16); \
                } else if (t0 == 48) { \
                    out[base + 47] = ACC[j][nt][0]; \
                    out[base + 48] = ACC[j][nt][1]; \
                    out[base + 49] = ACC[j][nt][2]; \
                } \
            } \
        } else if (colm < 556) { \
            int base = OFF_PRED + ((BP) * 300 + (colm - 256)) * 50; \
            _Pragma("unroll") \
            for (int nt = 0; nt < 4; nt++) { \
                int t0 = nt * 16 + lg * 4; \
                if (t0 <= 46) { \
                    f32x4 v = ACC[j][nt]; \
                    __builtin_memcpy(&out[base + t0], &v, 16); \
                } else if (t0 == 48) { \
                    out[base + 48] = ACC[j][nt][0]; \
                    out[base + 49] = ACC[j][nt][1]; \
                } \
            } \
        } \
    } }

    EPILOGUE(acc0, bp0);
    EPILOGUE(acc1, bp0 + 1);
#undef EPILOGUE
}

// ---- K2: X_U[b,i,t] = 0.5*(1+exp(-(B·U)[b,i,t])) * sum_p |X[b,p,i,t]|
__global__ void xu_kernel(const float* __restrict__ X, const float* __restrict__ U,
                          const float* __restrict__ B, float* __restrict__ out) {
    int id = blockIdx.x * 256 + threadIdx.x;
    if (id >= 480000) return;
    int t = id % 50;
    int i = (id / 50) % 300;
    int b = id / 15000;
    const float* xp = X + b * 960000 + i * 50 + t;
    float s = 0.f;
    #pragma unroll 8
    for (int pp = 0; pp < 64; pp++) s += fabsf(xp[pp * 15000]);
    float bu = 0.f;
    const float* up = U + b * 2000 + t;
    const float* Bp = B + i * 40;
    #pragma unroll 8
    for (int q = 0; q < 40; q++) bu += Bp[q] * up[q * 50];
    out[OFF_XU + id] = 0.5f * (1.f + expf(-bu)) * s;
}

extern "C" void kernel_launch(void* const* d_in, const int* in_sizes, int n_in,
                              void* d_out, int out_size, void* d_ws, size_t ws_size,
                              hipStream_t stream) {
    const float* X  = (const float*)d_in[0];
    const float* U  = (const float*)d_in[1];
    const float* x0 = (const float*)d_in[2];
    const float* A  = (const float*)d_in[3];
    const float* B  = (const float*)d_in[4];
    const float* C  = (const float*)d_in[5];
    float* out = (float*)d_out;
    unsigned* M = (unsigned*)d_ws;      // 640*320 fp8 = 204,800 B (fragment-ordered)

    build_M<<<200, 256, 0, stream>>>(A, C, M);
    gemm_main<<<2048, 256, 0, stream>>>(X, x0, (const char*)M, out);
    xu_kernel<<<1875, 256, 0, stream>>>(X, U, B, out);
}